// Round 9
// baseline (1783.832 us; speedup 1.0000x reference)
//
#include <hip/hip_runtime.h>
#include <hip/hip_bf16.h>

// ---------------------------------------------------------------------------
// HybridCnnLnn R9 = R8 + amdgpu_waves_per_eu(4,4) on lnn_kernel.
// R7/R8 lesson: __launch_bounds__'s 2nd arg is only a MINIMUM waves/EU; the
// allocator still targets 8 waves/EU (64 regs) and spills the working set
// (R8: VGPR=64 = exactly the param count, FETCH 2GB of scratch, 1588us).
// amdgpu_waves_per_eu(4,4) pins max occupancy = 4 waves/EU = 16 waves/CU =
// exactly our grid residency (256 blocks x 1024 thr = 1 block/CU), handing
// the allocator 128 regs with zero real occupancy cost.
// Arithmetic bit-identical to R8 (passed absmax 0.0).
// ---------------------------------------------------------------------------

#define L2E 1.4426950408889634f

__device__ __forceinline__ float sigfast(float z) {
  // 1/(1+2^z) ; |z| <= ~70 by data ranges -> no overflow paths
  return __builtin_amdgcn_rcpf(1.f + __builtin_amdgcn_exp2f(z));
}

// ---------------- prep: fold params, native [i][j] layout (identity) -------
__global__ __launch_bounds__(256)
void prep_kernel(const float* __restrict__ smu, const float* __restrict__ ssig,
                 const float* __restrict__ sW,  const float* __restrict__ serev,
                 const float* __restrict__ mu,  const float* __restrict__ sig,
                 const float* __restrict__ W,   const float* __restrict__ erev,
                 float2* __restrict__ MU2, float* __restrict__ VT,
                 float2* __restrict__ S2,  float* __restrict__ SV) {
  int idx = blockIdx.x * 256 + threadIdx.x;      // 64 blocks x 256 = 16384
  MU2[idx] = make_float2(mu[idx], sig[idx] * L2E);
  VT[idx]  = W[idx] * erev[idx];                 // |erev|=1 -> |VT| = W
  S2[idx]  = make_float2(smu[idx], ssig[idx] * L2E);
  SV[idx]  = sW[idx] * serev[idx];
}

// ----------------------------- conv1 (k=5, tiled) --------------------------
// x [512,256,24] -> P1 [512,64,128] ([b][co][t']), relu+maxpool2 fused
__launch_bounds__(512)
__global__ void conv1_kernel(const float* __restrict__ x, const float* __restrict__ w1,
                             const float* __restrict__ b1, float* __restrict__ P1) {
  __shared__ float xs[6240];                     // rows t in [-2,258), 24 ch
  int tid = threadIdx.x, b = blockIdx.x;
  const float* xb = x + (size_t)b * 6144;
  for (int idx = tid; idx < 6144; idx += 512) xs[idx + 48] = xb[idx];
  if (tid < 48) { xs[tid] = 0.f; xs[6192 + tid] = 0.f; }
  __syncthreads();
  int tp = tid & 127, cq = tid >> 7;             // 128 pooled t x 4 co-quarters
  float acc0[16], acc1[16];
#pragma unroll
  for (int n = 0; n < 16; n++) { float bb = b1[cq * 16 + n]; acc0[n] = bb; acc1[n] = bb; }
  for (int cic = 0; cic < 3; cic++) {            // ci chunks of 8
    float p[6][8];
#pragma unroll
    for (int r = 0; r < 6; r++) {
      const float* row = &xs[(2 * tp + r) * 24 + cic * 8];
      float4 a = *(const float4*)row;
      float4 c = *(const float4*)(row + 4);
      p[r][0] = a.x; p[r][1] = a.y; p[r][2] = a.z; p[r][3] = a.w;
      p[r][4] = c.x; p[r][5] = c.y; p[r][6] = c.z; p[r][7] = c.w;
    }
#pragma unroll
    for (int n = 0; n < 16; n++) {
      const float* wr = w1 + (cq * 16 + n) * 120 + cic * 40;  // uniform -> s_load
#pragma unroll
      for (int c = 0; c < 8; c++) {
#pragma unroll
        for (int kk = 0; kk < 5; kk++) {
          float w = wr[c * 5 + kk];
          acc0[n] = fmaf(p[kk][c],     w, acc0[n]);
          acc1[n] = fmaf(p[kk + 1][c], w, acc1[n]);
        }
      }
    }
  }
  float* pb = P1 + (size_t)b * 8192;
#pragma unroll
  for (int n = 0; n < 16; n++)
    pb[(cq * 16 + n) * 128 + tp] = fmaxf(fmaxf(acc0[n], acc1[n]), 0.f);
}

// ----------------------------- conv2 (k=3, tiled) --------------------------
// P1 [512,64,128] -> feats [512,64,128] laid out [b][t'][co]
__launch_bounds__(512)
__global__ void conv2_kernel(const float* __restrict__ P1, const float* __restrict__ w2,
                             const float* __restrict__ b2, float* __restrict__ feats) {
  __shared__ float xs[8450];                     // [t+1][ci], stride 65
  int tid = threadIdx.x, b = blockIdx.x;
  const float* pb = P1 + (size_t)b * 8192;
  for (int idx = tid; idx < 8192; idx += 512) {
    int ci = idx >> 7, t = idx & 127;
    xs[(t + 1) * 65 + ci] = pb[idx];
  }
  if (tid < 65) { xs[tid] = 0.f; xs[129 * 65 + tid] = 0.f; }
  __syncthreads();
  int tp = tid & 63, cq = tid >> 6;              // 64 pooled t x 8 co-octants
  float acc0[16], acc1[16];
#pragma unroll
  for (int n = 0; n < 16; n++) { float bb = b2[cq * 16 + n]; acc0[n] = bb; acc1[n] = bb; }
  for (int cic = 0; cic < 8; cic++) {            // ci chunks of 8
    float p[4][8];
#pragma unroll
    for (int r = 0; r < 4; r++)
#pragma unroll
      for (int c = 0; c < 8; c++)
        p[r][c] = xs[(2 * tp + r) * 65 + cic * 8 + c];
#pragma unroll
    for (int n = 0; n < 16; n++) {
      const float* wr = w2 + (cq * 16 + n) * 192 + cic * 24;  // native [co][ci][kk]
#pragma unroll
      for (int c = 0; c < 8; c++) {
#pragma unroll
        for (int kk = 0; kk < 3; kk++) {
          float w = wr[c * 3 + kk];
          acc0[n] = fmaf(p[kk][c],     w, acc0[n]);
          acc1[n] = fmaf(p[kk + 1][c], w, acc1[n]);
        }
      }
    }
  }
  __syncthreads();                               // reuse xs as [tp][co]
#pragma unroll
  for (int n = 0; n < 16; n += 4) {
    float4 v;
    v.x = fmaxf(fmaxf(acc0[n],     acc1[n]),     0.f);
    v.y = fmaxf(fmaxf(acc0[n + 1], acc1[n + 1]), 0.f);
    v.z = fmaxf(fmaxf(acc0[n + 2], acc1[n + 2]), 0.f);
    v.w = fmaxf(fmaxf(acc0[n + 3], acc1[n + 3]), 0.f);
    *(float4*)&xs[tp * 128 + cq * 16 + n] = v;
  }
  __syncthreads();
  float* fb = feats + (size_t)b * 8192;
  for (int idx = tid; idx < 8192; idx += 512) fb[idx] = xs[idx];
}

// --------------------------- LTC recurrence + head -------------------------
// block = 1024 threads: j = tid&127 (unit), h = tid>>7 (i-octant).
// 2 batches/block, grid 256 = 1 block/CU = 16 waves = 4 waves/EU.
// waves_per_eu(4,4): pins allocator budget to 128 VGPRs (no spill) at the
// occupancy the grid already enforces.
__attribute__((amdgpu_waves_per_eu(4, 4)))
__launch_bounds__(1024)
__global__ void lnn_kernel(const float2* __restrict__ MU2, const float* __restrict__ VT,
                           const float2* __restrict__ S2,  const float* __restrict__ SV,
                           const float* __restrict__ feats,
                           const float* __restrict__ in_w, const float* __restrict__ in_b,
                           const float* __restrict__ cm_t, const float* __restrict__ gleak,
                           const float* __restrict__ vleak,
                           const float* __restrict__ fc1_w, const float* __restrict__ fc1_b,
                           const float* __restrict__ fc2_w, const float* __restrict__ fc2_b,
                           float* __restrict__ out) {
  __shared__ float4 psum[8][128];
  __shared__ float2 vs2[128];
  __shared__ float2 xt2[128];
  __shared__ float red[2][64];
  int tid = threadIdx.x;
  int j = tid & 127, h = tid >> 7;               // h in [0,8)
  int b0 = blockIdx.x * 2;

  // recurrent params -> VGPRs (native layout, coalesced over j)
  float2 mu2[16]; float vw[16], sv[16];
#pragma unroll
  for (int n = 0; n < 16; n++) {
    int idx = (16 * h + n) * 128 + j;
    mu2[n] = MU2[idx];
    vw[n]  = VT[idx];
    sv[n]  = SV[idx];
  }
  float cmj = cm_t[j], glk = gleak[j];
  float gvl = glk * vleak[j], cgl = cmj + glk;
  float vj0 = 0.f, vj1 = 0.f;
  float iw = 0.f, ibb = 0.f;
  if (tid < 128) { iw = in_w[j]; ibb = in_b[j]; vs2[j] = make_float2(0.f, 0.f); }
  __syncthreads();

  for (int t = 0; t < 64; t++) {
    // stage xt for both batches (plain float2 store, no aliasing)
    if (tid < 128) {
      float a = feats[(size_t)b0 * 8192 + t * 128 + j];
      float b = feats[(size_t)(b0 + 1) * 8192 + t * 128 + j];
      xt2[j] = make_float2(fmaf(iw, a, ibb), fmaf(iw, b, ibb));
    }
    __syncthreads();

    // ---- sensory partials (S2 streamed from L2, sv in VGPRs) ----
    float sn0 = 0.f, sd0 = 0.f, sn1 = 0.f, sd1 = 0.f;
    {
      float n0 = 0.f, d0 = 0.f, n1 = 0.f, d1 = 0.f;
      const float2* sp = S2 + (size_t)(16 * h) * 128 + j;
#pragma unroll
      for (int n = 0; n < 16; n++) {
        float2 s = sp[n * 128];
        float2 xv = xt2[16 * h + n];
        float q0 = sigfast((s.x - xv.x) * s.y);
        n0 = fmaf(sv[n], q0, n0); d0 = fmaf(fabsf(sv[n]), q0, d0);
        float q1 = sigfast((s.x - xv.y) * s.y);
        n1 = fmaf(sv[n], q1, n1); d1 = fmaf(fabsf(sv[n]), q1, d1);
      }
      psum[h][j] = make_float4(n0, d0, n1, d1);
    }
    __syncthreads();
    if (h == 0) {                                // wave-uniform branch
      float4 a0 = psum[0][j], a1 = psum[1][j], a2 = psum[2][j], a3 = psum[3][j];
      float4 a4 = psum[4][j], a5 = psum[5][j], a6 = psum[6][j], a7 = psum[7][j];
      sn0 = a0.x + a1.x + a2.x + a3.x + a4.x + a5.x + a6.x + a7.x;
      sd0 = a0.y + a1.y + a2.y + a3.y + a4.y + a5.y + a6.y + a7.y;
      sn1 = a0.z + a1.z + a2.z + a3.z + a4.z + a5.z + a6.z + a7.z;
      sd1 = a0.w + a1.w + a2.w + a3.w + a4.w + a5.w + a6.w + a7.w;
    }
    __syncthreads();                             // psum reusable after this

    // ---- 6 semi-implicit ODE unfolds (params in VGPRs) ----
    for (int u = 0; u < 6; u++) {
      float n0 = 0.f, d0 = 0.f, n1 = 0.f, d1 = 0.f;
#pragma unroll
      for (int n = 0; n < 16; n++) {
        float2 v2 = vs2[16 * h + n];             // broadcast read
        float q0 = sigfast((mu2[n].x - v2.x) * mu2[n].y);
        n0 = fmaf(vw[n], q0, n0); d0 = fmaf(fabsf(vw[n]), q0, d0);
        float q1 = sigfast((mu2[n].x - v2.y) * mu2[n].y);
        n1 = fmaf(vw[n], q1, n1); d1 = fmaf(fabsf(vw[n]), q1, d1);
      }
      psum[h][j] = make_float4(n0, d0, n1, d1);
      __syncthreads();
      if (h == 0) {                              // wave-uniform
        float4 a0 = psum[0][j], a1 = psum[1][j], a2 = psum[2][j], a3 = psum[3][j];
        float4 a4 = psum[4][j], a5 = psum[5][j], a6 = psum[6][j], a7 = psum[7][j];
        float wn0 = sn0 + a0.x + a1.x + a2.x + a3.x + a4.x + a5.x + a6.x + a7.x;
        float wd0 = sd0 + a0.y + a1.y + a2.y + a3.y + a4.y + a5.y + a6.y + a7.y;
        float wn1 = sn1 + a0.z + a1.z + a2.z + a3.z + a4.z + a5.z + a6.z + a7.z;
        float wd1 = sd1 + a0.w + a1.w + a2.w + a3.w + a4.w + a5.w + a6.w + a7.w;
        vj0 = (fmaf(cmj, vj0, gvl) + wn0) / (cgl + wd0);
        vj1 = (fmaf(cmj, vj1, gvl) + wn1) / (cgl + wd1);
        vs2[j] = make_float2(vj0, vj1);
      }
      __syncthreads();
    }
  }

  // ---- MLP head (naive pattern: LDS red + sequential final sum) ----
  if (tid < 128) {
    int g = tid >> 6, d = tid & 63;
    float acc = fc1_b[d];
    for (int u = 0; u < 128; u++) {
      float2 v2 = vs2[u];
      acc = fmaf(g ? v2.y : v2.x, fc1_w[d * 128 + u], acc);
    }
    red[g][d] = fmaxf(acc, 0.f) * fc2_w[d];
  }
  __syncthreads();
  if (tid < 2) {
    float s = fc2_b[0];
    for (int d = 0; d < 64; d++) s += red[tid][d];
    out[b0 + tid] = s;
  }
}

// ------------------------------- launcher ----------------------------------
extern "C" void kernel_launch(void* const* d_in, const int* in_sizes, int n_in,
                              void* d_out, int out_size, void* d_ws, size_t ws_size,
                              hipStream_t stream) {
  (void)in_sizes; (void)n_in; (void)out_size; (void)ws_size;
  char* ws = (char*)d_ws;
  // Proven 32MB envelope, time-multiplexed:
  //   P1 [0,16M) live conv1->conv2; tables [0,384K) after conv2 (prep);
  //   feats [16M,32M) live conv2->lnn.
  float*  P1   = (float*)(ws);
  float*  feats= (float*)(ws + (16 << 20));
  float2* MU2  = (float2*)(ws + 0);             // 128KB
  float*  VT   = (float*)(ws + (128 << 10));    // 64KB
  float2* S2   = (float2*)(ws + (192 << 10));   // 128KB
  float*  SV   = (float*)(ws + (320 << 10));    // 64KB -> ends 384KB

  conv1_kernel<<<512, 512, 0, stream>>>((const float*)d_in[0],
      (const float*)d_in[1], (const float*)d_in[2], P1);
  conv2_kernel<<<512, 512, 0, stream>>>(P1,
      (const float*)d_in[3], (const float*)d_in[4], feats);
  prep_kernel<<<64, 256, 0, stream>>>(
      (const float*)d_in[7], (const float*)d_in[8],
      (const float*)d_in[9], (const float*)d_in[10],
      (const float*)d_in[11], (const float*)d_in[12],
      (const float*)d_in[13], (const float*)d_in[14],
      MU2, VT, S2, SV);
  lnn_kernel<<<256, 1024, 0, stream>>>(MU2, VT, S2, SV, feats,
      (const float*)d_in[5], (const float*)d_in[6],
      (const float*)d_in[17], (const float*)d_in[16], (const float*)d_in[15],
      (const float*)d_in[18], (const float*)d_in[19],
      (const float*)d_in[20], (const float*)d_in[21],
      (float*)d_out);
}

// Round 10
// 1311.017 us; speedup vs baseline: 1.3606x; 1.3606x over previous
//
#include <hip/hip_runtime.h>
#include <hip/hip_bf16.h>

// ---------------------------------------------------------------------------
// HybridCnnLnn R10: stop fighting the register allocator (R7/R8/R9: backend
// pins lnn at 64 arch-VGPRs; 2GB scratch FETCH). Restructure so 64 regs
// genuinely suffice: mu/sig table -> LDS (128KB, 1 block/CU owns 160KB),
// vw stays in 16 VGPRs, sv joins S2 in per-t L2 streaming. Per-thread demand
// ~55 regs -> no spill. Trans-pipe floor ~382us (2 trans/cell); LDS reads
// (stride-8B b64, conflict-free) hide under it.
// Arithmetic bit-identical to R9 (passed absmax 0.0).
// ---------------------------------------------------------------------------

#define L2E 1.4426950408889634f

__device__ __forceinline__ float sigfast(float z) {
  // 1/(1+2^z) ; |z| <= ~70 by data ranges -> no overflow paths
  return __builtin_amdgcn_rcpf(1.f + __builtin_amdgcn_exp2f(z));
}

// ---------------- prep: fold params, native [i][j] layout (identity) -------
__global__ __launch_bounds__(256)
void prep_kernel(const float* __restrict__ smu, const float* __restrict__ ssig,
                 const float* __restrict__ sW,  const float* __restrict__ serev,
                 const float* __restrict__ mu,  const float* __restrict__ sig,
                 const float* __restrict__ W,   const float* __restrict__ erev,
                 float2* __restrict__ MU2, float* __restrict__ VT,
                 float2* __restrict__ S2,  float* __restrict__ SV) {
  int idx = blockIdx.x * 256 + threadIdx.x;      // 64 blocks x 256 = 16384
  MU2[idx] = make_float2(mu[idx], sig[idx] * L2E);
  VT[idx]  = W[idx] * erev[idx];                 // |erev|=1 -> |VT| = W
  S2[idx]  = make_float2(smu[idx], ssig[idx] * L2E);
  SV[idx]  = sW[idx] * serev[idx];
}

// ----------------------------- conv1 (k=5, tiled) --------------------------
// x [512,256,24] -> P1 [512,64,128] ([b][co][t']), relu+maxpool2 fused
__launch_bounds__(512)
__global__ void conv1_kernel(const float* __restrict__ x, const float* __restrict__ w1,
                             const float* __restrict__ b1, float* __restrict__ P1) {
  __shared__ float xs[6240];                     // rows t in [-2,258), 24 ch
  int tid = threadIdx.x, b = blockIdx.x;
  const float* xb = x + (size_t)b * 6144;
  for (int idx = tid; idx < 6144; idx += 512) xs[idx + 48] = xb[idx];
  if (tid < 48) { xs[tid] = 0.f; xs[6192 + tid] = 0.f; }
  __syncthreads();
  int tp = tid & 127, cq = tid >> 7;             // 128 pooled t x 4 co-quarters
  float acc0[16], acc1[16];
#pragma unroll
  for (int n = 0; n < 16; n++) { float bb = b1[cq * 16 + n]; acc0[n] = bb; acc1[n] = bb; }
  for (int cic = 0; cic < 3; cic++) {            // ci chunks of 8
    float p[6][8];
#pragma unroll
    for (int r = 0; r < 6; r++) {
      const float* row = &xs[(2 * tp + r) * 24 + cic * 8];
      float4 a = *(const float4*)row;
      float4 c = *(const float4*)(row + 4);
      p[r][0] = a.x; p[r][1] = a.y; p[r][2] = a.z; p[r][3] = a.w;
      p[r][4] = c.x; p[r][5] = c.y; p[r][6] = c.z; p[r][7] = c.w;
    }
#pragma unroll
    for (int n = 0; n < 16; n++) {
      const float* wr = w1 + (cq * 16 + n) * 120 + cic * 40;  // uniform -> s_load
#pragma unroll
      for (int c = 0; c < 8; c++) {
#pragma unroll
        for (int kk = 0; kk < 5; kk++) {
          float w = wr[c * 5 + kk];
          acc0[n] = fmaf(p[kk][c],     w, acc0[n]);
          acc1[n] = fmaf(p[kk + 1][c], w, acc1[n]);
        }
      }
    }
  }
  float* pb = P1 + (size_t)b * 8192;
#pragma unroll
  for (int n = 0; n < 16; n++)
    pb[(cq * 16 + n) * 128 + tp] = fmaxf(fmaxf(acc0[n], acc1[n]), 0.f);
}

// ----------------------------- conv2 (k=3, tiled) --------------------------
// P1 [512,64,128] -> feats [512,64,128] laid out [b][t'][co]
__launch_bounds__(512)
__global__ void conv2_kernel(const float* __restrict__ P1, const float* __restrict__ w2,
                             const float* __restrict__ b2, float* __restrict__ feats) {
  __shared__ float xs[8450];                     // [t+1][ci], stride 65
  int tid = threadIdx.x, b = blockIdx.x;
  const float* pb = P1 + (size_t)b * 8192;
  for (int idx = tid; idx < 8192; idx += 512) {
    int ci = idx >> 7, t = idx & 127;
    xs[(t + 1) * 65 + ci] = pb[idx];
  }
  if (tid < 65) { xs[tid] = 0.f; xs[129 * 65 + tid] = 0.f; }
  __syncthreads();
  int tp = tid & 63, cq = tid >> 6;              // 64 pooled t x 8 co-octants
  float acc0[16], acc1[16];
#pragma unroll
  for (int n = 0; n < 16; n++) { float bb = b2[cq * 16 + n]; acc0[n] = bb; acc1[n] = bb; }
  for (int cic = 0; cic < 8; cic++) {            // ci chunks of 8
    float p[4][8];
#pragma unroll
    for (int r = 0; r < 4; r++)
#pragma unroll
      for (int c = 0; c < 8; c++)
        p[r][c] = xs[(2 * tp + r) * 65 + cic * 8 + c];
#pragma unroll
    for (int n = 0; n < 16; n++) {
      const float* wr = w2 + (cq * 16 + n) * 192 + cic * 24;  // native [co][ci][kk]
#pragma unroll
      for (int c = 0; c < 8; c++) {
#pragma unroll
        for (int kk = 0; kk < 3; kk++) {
          float w = wr[c * 3 + kk];
          acc0[n] = fmaf(p[kk][c],     w, acc0[n]);
          acc1[n] = fmaf(p[kk + 1][c], w, acc1[n]);
        }
      }
    }
  }
  __syncthreads();                               // reuse xs as [tp][co]
#pragma unroll
  for (int n = 0; n < 16; n += 4) {
    float4 v;
    v.x = fmaxf(fmaxf(acc0[n],     acc1[n]),     0.f);
    v.y = fmaxf(fmaxf(acc0[n + 1], acc1[n + 1]), 0.f);
    v.z = fmaxf(fmaxf(acc0[n + 2], acc1[n + 2]), 0.f);
    v.w = fmaxf(fmaxf(acc0[n + 3], acc1[n + 3]), 0.f);
    *(float4*)&xs[tp * 128 + cq * 16 + n] = v;
  }
  __syncthreads();
  float* fb = feats + (size_t)b * 8192;
  for (int idx = tid; idx < 8192; idx += 512) fb[idx] = xs[idx];
}

// --------------------------- LTC recurrence + head -------------------------
// block = 1024 threads: j = tid&127 (unit), h = tid>>7 (i-octant).
// 2 batches/block, grid 256 = 1 block/CU (LDS 147KB also caps at 1 block/CU).
// mu/sig in LDS; vw in 16 VGPRs; sensory S2/SV streamed from L2 per t.
__launch_bounds__(1024)
__global__ void lnn_kernel(const float2* __restrict__ MU2, const float* __restrict__ VT,
                           const float2* __restrict__ S2,  const float* __restrict__ SV,
                           const float* __restrict__ feats,
                           const float* __restrict__ in_w, const float* __restrict__ in_b,
                           const float* __restrict__ cm_t, const float* __restrict__ gleak,
                           const float* __restrict__ vleak,
                           const float* __restrict__ fc1_w, const float* __restrict__ fc1_b,
                           const float* __restrict__ fc2_w, const float* __restrict__ fc2_b,
                           float* __restrict__ out) {
  __shared__ float2 mu2lds[16384];               // 128KB: (mu, sig*L2E)[i][j]
  __shared__ float4 psum[8][128];                // 16KB
  __shared__ float2 vs2[128];
  __shared__ float2 xt2[128];
  __shared__ float red[2][64];
  int tid = threadIdx.x;
  int j = tid & 127, h = tid >> 7;               // h in [0,8)
  int b0 = blockIdx.x * 2;

  // stage mu/sig table into LDS (16 coalesced float2 iters)
  for (int idx = tid; idx < 16384; idx += 1024) mu2lds[idx] = MU2[idx];

  // vw -> VGPRs (16 regs; coalesced over j)
  float vw[16];
#pragma unroll
  for (int n = 0; n < 16; n++) vw[n] = VT[(16 * h + n) * 128 + j];

  float cmj = cm_t[j], glk = gleak[j];
  float gvl = glk * vleak[j], cgl = cmj + glk;
  float vj0 = 0.f, vj1 = 0.f;
  float iw = 0.f, ibb = 0.f;
  if (tid < 128) { iw = in_w[j]; ibb = in_b[j]; vs2[j] = make_float2(0.f, 0.f); }
  __syncthreads();

  for (int t = 0; t < 64; t++) {
    // stage xt for both batches
    if (tid < 128) {
      float a = feats[(size_t)b0 * 8192 + t * 128 + j];
      float b = feats[(size_t)(b0 + 1) * 8192 + t * 128 + j];
      xt2[j] = make_float2(fmaf(iw, a, ibb), fmaf(iw, b, ibb));
    }
    __syncthreads();

    // ---- sensory partials (S2 + SV streamed from L2) ----
    float sn0 = 0.f, sd0 = 0.f, sn1 = 0.f, sd1 = 0.f;
    {
      float n0 = 0.f, d0 = 0.f, n1 = 0.f, d1 = 0.f;
      const float2* sp = S2 + (size_t)(16 * h) * 128 + j;
      const float*  vp = SV + (size_t)(16 * h) * 128 + j;
#pragma unroll 8
      for (int n = 0; n < 16; n++) {
        float2 s = sp[n * 128];
        float svv = vp[n * 128];
        float2 xv = xt2[16 * h + n];
        float q0 = sigfast((s.x - xv.x) * s.y);
        n0 = fmaf(svv, q0, n0); d0 = fmaf(fabsf(svv), q0, d0);
        float q1 = sigfast((s.x - xv.y) * s.y);
        n1 = fmaf(svv, q1, n1); d1 = fmaf(fabsf(svv), q1, d1);
      }
      psum[h][j] = make_float4(n0, d0, n1, d1);
    }
    __syncthreads();
    if (h == 0) {                                // wave-uniform branch
      float4 a0 = psum[0][j], a1 = psum[1][j], a2 = psum[2][j], a3 = psum[3][j];
      float4 a4 = psum[4][j], a5 = psum[5][j], a6 = psum[6][j], a7 = psum[7][j];
      sn0 = a0.x + a1.x + a2.x + a3.x + a4.x + a5.x + a6.x + a7.x;
      sd0 = a0.y + a1.y + a2.y + a3.y + a4.y + a5.y + a6.y + a7.y;
      sn1 = a0.z + a1.z + a2.z + a3.z + a4.z + a5.z + a6.z + a7.z;
      sd1 = a0.w + a1.w + a2.w + a3.w + a4.w + a5.w + a6.w + a7.w;
    }
    __syncthreads();                             // psum reusable after this

    // ---- 6 semi-implicit ODE unfolds (mu/sig from LDS, vw in VGPRs) ----
    for (int u = 0; u < 6; u++) {
      float n0 = 0.f, d0 = 0.f, n1 = 0.f, d1 = 0.f;
      const float2* mp = &mu2lds[(16 * h) * 128 + j];
#pragma unroll
      for (int n = 0; n < 16; n++) {
        float2 m2 = mp[n * 128];                 // stride-8B b64, conflict-free
        float2 v2 = vs2[16 * h + n];             // broadcast read
        float q0 = sigfast((m2.x - v2.x) * m2.y);
        n0 = fmaf(vw[n], q0, n0); d0 = fmaf(fabsf(vw[n]), q0, d0);
        float q1 = sigfast((m2.x - v2.y) * m2.y);
        n1 = fmaf(vw[n], q1, n1); d1 = fmaf(fabsf(vw[n]), q1, d1);
      }
      psum[h][j] = make_float4(n0, d0, n1, d1);
      __syncthreads();
      if (h == 0) {                              // wave-uniform
        float4 a0 = psum[0][j], a1 = psum[1][j], a2 = psum[2][j], a3 = psum[3][j];
        float4 a4 = psum[4][j], a5 = psum[5][j], a6 = psum[6][j], a7 = psum[7][j];
        float wn0 = sn0 + a0.x + a1.x + a2.x + a3.x + a4.x + a5.x + a6.x + a7.x;
        float wd0 = sd0 + a0.y + a1.y + a2.y + a3.y + a4.y + a5.y + a6.y + a7.y;
        float wn1 = sn1 + a0.z + a1.z + a2.z + a3.z + a4.z + a5.z + a6.z + a7.z;
        float wd1 = sd1 + a0.w + a1.w + a2.w + a3.w + a4.w + a5.w + a6.w + a7.w;
        vj0 = (fmaf(cmj, vj0, gvl) + wn0) / (cgl + wd0);
        vj1 = (fmaf(cmj, vj1, gvl) + wn1) / (cgl + wd1);
        vs2[j] = make_float2(vj0, vj1);
      }
      __syncthreads();
    }
  }

  // ---- MLP head (naive pattern: LDS red + sequential final sum) ----
  if (tid < 128) {
    int g = tid >> 6, d = tid & 63;
    float acc = fc1_b[d];
    for (int u = 0; u < 128; u++) {
      float2 v2 = vs2[u];
      acc = fmaf(g ? v2.y : v2.x, fc1_w[d * 128 + u], acc);
    }
    red[g][d] = fmaxf(acc, 0.f) * fc2_w[d];
  }
  __syncthreads();
  if (tid < 2) {
    float s = fc2_b[0];
    for (int d = 0; d < 64; d++) s += red[tid][d];
    out[b0 + tid] = s;
  }
}

// ------------------------------- launcher ----------------------------------
extern "C" void kernel_launch(void* const* d_in, const int* in_sizes, int n_in,
                              void* d_out, int out_size, void* d_ws, size_t ws_size,
                              hipStream_t stream) {
  (void)in_sizes; (void)n_in; (void)out_size; (void)ws_size;
  char* ws = (char*)d_ws;
  // Proven 32MB envelope, time-multiplexed:
  //   P1 [0,16M) live conv1->conv2; tables [0,384K) after conv2 (prep);
  //   feats [16M,32M) live conv2->lnn.
  float*  P1   = (float*)(ws);
  float*  feats= (float*)(ws + (16 << 20));
  float2* MU2  = (float2*)(ws + 0);             // 128KB
  float*  VT   = (float*)(ws + (128 << 10));    // 64KB
  float2* S2   = (float2*)(ws + (192 << 10));   // 128KB
  float*  SV   = (float*)(ws + (320 << 10));    // 64KB -> ends 384KB

  conv1_kernel<<<512, 512, 0, stream>>>((const float*)d_in[0],
      (const float*)d_in[1], (const float*)d_in[2], P1);
  conv2_kernel<<<512, 512, 0, stream>>>(P1,
      (const float*)d_in[3], (const float*)d_in[4], feats);
  prep_kernel<<<64, 256, 0, stream>>>(
      (const float*)d_in[7], (const float*)d_in[8],
      (const float*)d_in[9], (const float*)d_in[10],
      (const float*)d_in[11], (const float*)d_in[12],
      (const float*)d_in[13], (const float*)d_in[14],
      MU2, VT, S2, SV);
  lnn_kernel<<<256, 1024, 0, stream>>>(MU2, VT, S2, SV, feats,
      (const float*)d_in[5], (const float*)d_in[6],
      (const float*)d_in[17], (const float*)d_in[16], (const float*)d_in[15],
      (const float*)d_in[18], (const float*)d_in[19],
      (const float*)d_in[20], (const float*)d_in[21],
      (float*)d_out);
}